// Round 2
// baseline (243.353 us; speedup 1.0000x reference)
//
#include <hip/hip_runtime.h>

#define BATCH 64
#define HH 512
#define WW 512
#define TH 32                    // output rows per strip
#define KS 11
#define PADK 5
#define NIN (TH + 2 * PADK)      // 42 input rows per strip
#define NCHK 4                   // 11-row chunks (44 slots, tail guarded)
#define PADL 5
#define LROW2 (PADL + WW + PADL) // 522 float2 slots per staged row
#define NPIX (64.0 * 512.0 * 512.0)

// One block: 256 threads; thread t owns output columns 2t, 2t+1 of a strip of
// TH=32 rows. Staging is float2{a,b} (8 B/px); q=a^2+b^2, p=ab are recomputed
// at read time so one ds_read_b128 covers TWO pixels of the shared 12-px
// horizontal window -> 6 b128 reads per input row per thread (vs 22 for the
// float4 scheme). Vertical 11-tap ring is statically indexed because chunks
// are exactly KS=11 rows: ring slot == row-within-chunk. Outer chunk loop is
// NOT unrolled (I-cache); all ring/mod indices stay compile-time anyway.
// s2 is force-aligned to 16 B: ds_read_b128 via the float4 reinterpret needs
// it (float2 alone only guarantees 8 B; row stride 4176 B is 16-divisible).
__global__ void __launch_bounds__(256, 3) ssim_main_kernel(
    const float* __restrict__ img1, const float* __restrict__ img2,
    double* __restrict__ accum) {
  // Gaussian(sigma=1.5, K=11), normalized (fp64-precomputed).
  constexpr float G[KS] = {
      0.00102838f, 0.00759884f, 0.03600087f, 0.10936069f, 0.21300553f,
      0.26601172f, 0.21300553f, 0.10936069f, 0.03600087f, 0.00759884f,
      0.00102838f};
  const float C1 = 1e-4f, C2 = 9e-4f;

  const int t  = threadIdx.x;          // 0..255
  const int r0 = blockIdx.x * TH;      // first output row of strip
  const int b  = blockIdx.y;           // batch index

  const float2* __restrict__ pp1 =
      reinterpret_cast<const float2*>(img1 + (size_t)b * HH * WW);
  const float2* __restrict__ pp2 =
      reinterpret_cast<const float2*>(img2 + (size_t)b * HH * WW);

  // Single-buffered 11-row staging window; pixel x lives at slot x+PADL so
  // thread t's window (px 2t-5 .. 2t+6) = slots 2t..2t+11 -> 6 aligned b128.
  __shared__ __align__(16) float2 s2[KS][LROW2];
  __shared__ float wsum[256 / 64];

  // Zero horizontal pads once (slots 0..4 and 517..521; never overwritten).
  if (t < 2 * PADK) {
    const int slot = (t < PADK) ? t : (WW + PADL + t - PADK);
#pragma unroll
    for (int r = 0; r < KS; ++r) s2[r][slot] = make_float2(0.f, 0.f);
  }

  // Vertical ring: slot p holds h-conv of chunk-row p. 4 signals x 2 cols.
  float rA[2][KS], rB[2][KS], rQ[2][KS], rP[2][KS];
  float2 qa[6], qb[6];   // async-stage registers (half-chunk: 6 or 5 rows)
  float local = 0.f;

  // Load half-chunk (rows p0..p0+n-1 of chunk cn) into qa/qb. Row validity is
  // block-uniform -> scalar branch. Rows past NIN skipped (saves fetch).
#define LOADHALF(cn_, p0_, n_)                                           \
  {                                                                      \
    const int cb_ = 11 * (cn_) + (p0_);                                  \
    _Pragma("unroll")                                                    \
    for (int j = 0; j < (n_); ++j) {                                     \
      const int rr_ = r0 - PADK + cb_ + j;                               \
      qa[j] = make_float2(0.f, 0.f);                                     \
      qb[j] = make_float2(0.f, 0.f);                                     \
      if (rr_ >= 0 && rr_ < HH && (cb_ + j) < NIN) {                     \
        qa[j] = pp1[(size_t)rr_ * (WW / 2) + t];                         \
        qb[j] = pp2[(size_t)rr_ * (WW / 2) + t];                         \
      }                                                                  \
    }                                                                    \
  }

  // Write staged registers to LDS slots p0..p0+n-1 (two ds_write_b64 / row).
#define WRITEHALF(p0_, n_)                                               \
  {                                                                      \
    _Pragma("unroll")                                                    \
    for (int j = 0; j < (n_); ++j) {                                     \
      s2[(p0_) + j][PADL + 2 * t]     = make_float2(qa[j].x, qb[j].x);   \
      s2[(p0_) + j][PADL + 2 * t + 1] = make_float2(qa[j].y, qb[j].y);   \
    }                                                                    \
  }

  // Process rows p0..p0+n-1 of chunk o: 6 b128 reads, 12 px products,
  // 2x 11-tap h-conv, ring store, and (when ready) vertical conv + SSIM.
#define ROWS(o_, p0_, n_)                                                \
  {                                                                      \
    _Pragma("unroll")                                                    \
    for (int pj = 0; pj < (n_); ++pj) {                                  \
      const int p_ = (p0_) + pj;         /* static after unroll */       \
      const int i_ = 11 * (o_) + p_;     /* block-uniform */             \
      if (i_ < NIN) {                                                    \
        const float4* r4_ = reinterpret_cast<const float4*>(&s2[p_][0]); \
        float ax[12], bx[12];                                            \
        _Pragma("unroll")                                                \
        for (int k = 0; k < 6; ++k) {                                    \
          const float4 v_ = r4_[t + k];                                  \
          ax[2 * k]     = v_.x; bx[2 * k]     = v_.y;                    \
          ax[2 * k + 1] = v_.z; bx[2 * k + 1] = v_.w;                    \
        }                                                                \
        float h0a = 0.f, h0b = 0.f, h0q = 0.f, h0p = 0.f;                \
        float h1a = 0.f, h1b = 0.f, h1q = 0.f, h1p = 0.f;                \
        _Pragma("unroll")                                                \
        for (int j = 0; j < 12; ++j) {                                   \
          const float qv_ = fmaf(ax[j], ax[j], bx[j] * bx[j]);           \
          const float pv_ = ax[j] * bx[j];                               \
          if (j < KS) {                                                  \
            const float w_ = G[j];                                       \
            h0a = fmaf(w_, ax[j], h0a); h0b = fmaf(w_, bx[j], h0b);      \
            h0q = fmaf(w_, qv_, h0q);   h0p = fmaf(w_, pv_, h0p);        \
          }                                                              \
          if (j >= 1) {                                                  \
            const float w_ = G[j - 1];                                   \
            h1a = fmaf(w_, ax[j], h1a); h1b = fmaf(w_, bx[j], h1b);      \
            h1q = fmaf(w_, qv_, h1q);   h1p = fmaf(w_, pv_, h1p);        \
          }                                                              \
        }                                                                \
        rA[0][p_] = h0a; rB[0][p_] = h0b; rQ[0][p_] = h0q; rP[0][p_] = h0p; \
        rA[1][p_] = h1a; rB[1][p_] = h1b; rQ[1][p_] = h1q; rP[1][p_] = h1p; \
        if (i_ >= 2 * PADK) {                                            \
          /* output row i_-10: taps at ring slot (p_+1+tt)%11, static */ \
          _Pragma("unroll")                                              \
          for (int u = 0; u < 2; ++u) {                                  \
            float m1 = 0.f, m2 = 0.f, mq = 0.f, mp = 0.f;                \
            _Pragma("unroll")                                            \
            for (int tt = 0; tt < KS; ++tt) {                            \
              const int sl_ = (p_ + 1 + tt) % KS;                        \
              const float w_ = G[tt];                                    \
              m1 = fmaf(w_, rA[u][sl_], m1);                             \
              m2 = fmaf(w_, rB[u][sl_], m2);                             \
              mq = fmaf(w_, rQ[u][sl_], mq);                             \
              mp = fmaf(w_, rP[u][sl_], mp);                             \
            }                                                            \
            const float m1s = m1 * m1, m2s = m2 * m2, m12 = m1 * m2;     \
            const float s12 = mp - m12;                                  \
            const float sqq = mq - m1s - m2s;                            \
            const float num = fmaf(2.f, m12, C1) * fmaf(2.f, s12, C2);   \
            const float den = (m1s + m2s + C1) * (sqq + C2);             \
            local = fmaf(num, __builtin_amdgcn_rcpf(den), local);        \
          }                                                              \
        }                                                                \
      }                                                                  \
    }                                                                    \
  }

  // Prologue: stage chunk 0 fully (all writes precede the first barrier).
  LOADHALF(0, 0, 6);
  WRITEHALF(0, 6);
  LOADHALF(0, 6, 5);
  WRITEHALF(6, 5);
  __syncthreads();

  // Steady state, 2 barriers/chunk. Loads for the NEXT half-chunk are issued
  // before the compute phase (latency hides under ~750 VALU ops), the LDS
  // write lands right after the barrier that retires the old readers.
#pragma unroll 1
  for (int o = 0; o < NCHK; ++o) {
    const int nx = o + 1;
    if (nx < NCHK) LOADHALF(nx, 0, 6);
    ROWS(o, 0, 6);
    __syncthreads();
    if (nx < NCHK) WRITEHALF(0, 6);
    if (nx < NCHK) LOADHALF(nx, 6, 5);
    ROWS(o, 6, 5);
    __syncthreads();
    if (nx < NCHK) WRITEHALF(6, 5);
  }

  // Block reduction: wave64 shuffle -> LDS -> one double atomic per block.
#pragma unroll
  for (int off = 32; off > 0; off >>= 1) local += __shfl_down(local, off, 64);
  const int wave = t >> 6;
  const int lane = t & 63;
  if (lane == 0) wsum[wave] = local;
  __syncthreads();
  if (t == 0) {
    float s = wsum[0] + wsum[1] + wsum[2] + wsum[3];
    atomicAdd(accum, (double)s);
  }
}

__global__ void ssim_final_kernel(const double* __restrict__ accum,
                                  float* __restrict__ out) {
  out[0] = 1.0f - (float)(accum[0] / NPIX);
}

extern "C" void kernel_launch(void* const* d_in, const int* in_sizes, int n_in,
                              void* d_out, int out_size, void* d_ws, size_t ws_size,
                              hipStream_t stream) {
  const float* img1 = (const float*)d_in[0];
  const float* img2 = (const float*)d_in[1];
  double* accum = (double*)d_ws;
  hipMemsetAsync(accum, 0, sizeof(double), stream);

  dim3 grid(HH / TH, BATCH);
  ssim_main_kernel<<<grid, 256, 0, stream>>>(img1, img2, accum);
  ssim_final_kernel<<<1, 1, 0, stream>>>(accum, (float*)d_out);
}

// Round 3
// 224.585 us; speedup vs baseline: 1.0836x; 1.0836x over previous
//
#include <hip/hip_runtime.h>

#define BATCH 64
#define HH 512
#define WW 512
#define TH 32                  // output rows per strip
#define KS 11
#define PADK 5
#define NIN (TH + 2 * PADK)    // 42 input rows per strip
#define NCHK 4                 // 11-row chunks (44 slots, tail guarded)
#define NF4 262                // float4 slots per staged row: 6+512+6 float2 halves
#define NPIX (64.0 * 512.0 * 512.0)

// One block: 256 threads; thread t owns output columns 2t, 2t+1 of a strip of
// TH=32 rows. LDS staging is float4{a0,b0,a1,b1} per 2 pixels (native float4
// array: slot t+3 write is 16B-aligned ds_write_b128, stride 16 -> zero bank
// conflicts; reads are 7 aligned b128 covering the shared 14-px window).
// q=a^2+b^2, p=ab recomputed at read time. Vertical 11-tap ring is 88 NAMED
// scalar floats (no arrays anywhere in per-thread state): LLVM SROA runs
// before the unroller, so array-based rings with "static after unroll"
// indices land in scratch (round-0/2 post-mortem: 53/132 MB WRITE_SIZE).
__global__ void __launch_bounds__(256, 2) ssim_main_kernel(
    const float* __restrict__ img1, const float* __restrict__ img2,
    double* __restrict__ accum) {
  constexpr float GA[KS] = {
      0.00102838f, 0.00759884f, 0.03600087f, 0.10936069f, 0.21300553f,
      0.26601172f, 0.21300553f, 0.10936069f, 0.03600087f, 0.00759884f,
      0.00102838f};
  const float C1v = 1e-4f, C2v = 9e-4f;

  const int t  = threadIdx.x;          // 0..255
  const int r0 = blockIdx.x * TH;      // first output row of strip
  const int b  = blockIdx.y;           // batch index

  const float2* __restrict__ pp1 =
      reinterpret_cast<const float2*>(img1 + (size_t)b * HH * WW);
  const float2* __restrict__ pp2 =
      reinterpret_cast<const float2*>(img2 + (size_t)b * HH * WW);

  // 11-row staging window. Pixel pair (2x,2x+1) -> float4 slot x+3.
  __shared__ float4 s2[KS][NF4];
  __shared__ float wsum[4];

  // Zero horizontal pads (f4 slots 0..2 = px -6..-1, 259..261 = px 512..517).
  if (t < 6) {
    const int idx = (t < 3) ? t : (256 + t);
#pragma unroll
    for (int r = 0; r < KS; ++r) s2[r][idx] = make_float4(0.f, 0.f, 0.f, 0.f);
  }

  // Ring: 88 named scalars. Slot p holds h-conv of input row i with i%11==p.
#define DECLR(p) float xA##p = 0.f, xB##p = 0.f, xQ##p = 0.f, xP##p = 0.f, \
                       yA##p = 0.f, yB##p = 0.f, yQ##p = 0.f, yP##p = 0.f;
  DECLR(0) DECLR(1) DECLR(2) DECLR(3) DECLR(4) DECLR(5)
  DECLR(6) DECLR(7) DECLR(8) DECLR(9) DECLR(10)

  float2 qa0, qa1, qa2, qa3, qa4, qa5, qb0, qb1, qb2, qb3, qb4, qb5;
  float local = 0.f;

  // --- staging macros (named regs; row validity is block-uniform) ---
#define GL1(qA_, qB_, rowc_)                                        \
  {                                                                 \
    const int rc_ = (rowc_);                                        \
    const int rr_ = r0 - PADK + rc_;                                \
    qA_ = make_float2(0.f, 0.f);                                    \
    qB_ = make_float2(0.f, 0.f);                                    \
    if (rc_ < NIN && (unsigned)rr_ < HH) {                          \
      const int off_ = rr_ * (WW / 2) + t;                          \
      qA_ = pp1[off_];                                              \
      qB_ = pp2[off_];                                              \
    }                                                               \
  }
#define LOAD6(cn_) { GL1(qa0, qb0, 11*(cn_)+0) GL1(qa1, qb1, 11*(cn_)+1) \
                     GL1(qa2, qb2, 11*(cn_)+2) GL1(qa3, qb3, 11*(cn_)+3) \
                     GL1(qa4, qb4, 11*(cn_)+4) GL1(qa5, qb5, 11*(cn_)+5) }
#define LOAD5(cn_) { GL1(qa0, qb0, 11*(cn_)+6) GL1(qa1, qb1, 11*(cn_)+7) \
                     GL1(qa2, qb2, 11*(cn_)+8) GL1(qa3, qb3, 11*(cn_)+9) \
                     GL1(qa4, qb4, 11*(cn_)+10) }
#define WL1(p_, qA_, qB_) s2[p_][t + 3] = make_float4(qA_.x, qB_.x, qA_.y, qB_.y);
#define WRITE6 { WL1(0, qa0, qb0) WL1(1, qa1, qb1) WL1(2, qa2, qb2) \
                 WL1(3, qa3, qb3) WL1(4, qa4, qb4) WL1(5, qa5, qb5) }
#define WRITE5 { WL1(6, qa0, qb0) WL1(7, qa1, qb1) WL1(8, qa2, qb2) \
                 WL1(9, qa3, qb3) WL1(10, qa4, qb4) }

  // --- horizontal conv of row p: 7 b128 reads streamed into 8 accumulators.
  // f4 slot t+kk = px pair (j0=2kk-1, j1=2kk) relative to window start 2t-5.
  // col0 (2t): weight GA[j], j in [0,10]; col1 (2t+1): GA[j-1], j in [1,11].
#define HBODY(p)                                                              \
  {                                                                           \
    float h0a = 0.f, h0b = 0.f, h0q = 0.f, h0p = 0.f;                         \
    float h1a = 0.f, h1b = 0.f, h1q = 0.f, h1p = 0.f;                         \
    _Pragma("unroll")                                                         \
    for (int kk = 0; kk < 7; ++kk) {                                          \
      const float4 v = s2[p][t + kk];                                         \
      if (kk >= 1) {  /* px j0 = 2kk-1 : a=v.x b=v.y */                       \
        const float qv_ = fmaf(v.x, v.x, v.y * v.y);                          \
        const float pv_ = v.x * v.y;                                          \
        if (kk <= 5) {                                                        \
          const float w = GA[2 * kk - 1];                                     \
          h0a = fmaf(w, v.x, h0a); h0b = fmaf(w, v.y, h0b);                   \
          h0q = fmaf(w, qv_, h0q); h0p = fmaf(w, pv_, h0p);                   \
        }                                                                     \
        {                                                                     \
          const float w = GA[2 * kk - 2];                                     \
          h1a = fmaf(w, v.x, h1a); h1b = fmaf(w, v.y, h1b);                   \
          h1q = fmaf(w, qv_, h1q); h1p = fmaf(w, pv_, h1p);                   \
        }                                                                     \
      }                                                                       \
      if (kk <= 5) {  /* px j1 = 2kk : a=v.z b=v.w */                         \
        const float qv_ = fmaf(v.z, v.z, v.w * v.w);                          \
        const float pv_ = v.z * v.w;                                          \
        {                                                                     \
          const float w = GA[2 * kk];                                         \
          h0a = fmaf(w, v.z, h0a); h0b = fmaf(w, v.w, h0b);                   \
          h0q = fmaf(w, qv_, h0q); h0p = fmaf(w, pv_, h0p);                   \
        }                                                                     \
        if (kk >= 1) {                                                        \
          const float w = GA[2 * kk - 1];                                     \
          h1a = fmaf(w, v.z, h1a); h1b = fmaf(w, v.w, h1b);                   \
          h1q = fmaf(w, qv_, h1q); h1p = fmaf(w, pv_, h1p);                   \
        }                                                                     \
      }                                                                       \
    }                                                                         \
    xA##p = h0a; xB##p = h0b; xQ##p = h0q; xP##p = h0p;                       \
    yA##p = h1a; yB##p = h1b; yQ##p = h1q; yP##p = h1p;                       \
  }

  // --- vertical conv: explicit rotation, all slot names literal ---
#define VC(P, s0,s1,s2_,s3,s4,s5,s6,s7,s8,s9,s10)                             \
  fmaf(GA[10], P##s10, fmaf(GA[9], P##s9, fmaf(GA[8], P##s8,                  \
  fmaf(GA[7], P##s7, fmaf(GA[6], P##s6, fmaf(GA[5], P##s5,                    \
  fmaf(GA[4], P##s4, fmaf(GA[3], P##s3, fmaf(GA[2], P##s2_,                   \
  fmaf(GA[1], P##s1, GA[0] * P##s0))))))))))

#define SSIMACC                                                               \
  {                                                                           \
    const float m1s = m1 * m1, m2s = m2 * m2, m12 = m1 * m2;                  \
    const float s12 = mp - m12;                                               \
    const float sqq = mq - m1s - m2s;                                         \
    const float num = fmaf(2.f, m12, C1v) * fmaf(2.f, s12, C2v);              \
    const float den = (m1s + m2s + C1v) * (sqq + C2v);                        \
    local = fmaf(num, __builtin_amdgcn_rcpf(den), local);                     \
  }

#define VOUTBODY(s0,s1,s2_,s3,s4,s5,s6,s7,s8,s9,s10)                          \
  {                                                                           \
    {                                                                         \
      const float m1 = VC(xA, s0,s1,s2_,s3,s4,s5,s6,s7,s8,s9,s10);            \
      const float m2 = VC(xB, s0,s1,s2_,s3,s4,s5,s6,s7,s8,s9,s10);            \
      const float mq = VC(xQ, s0,s1,s2_,s3,s4,s5,s6,s7,s8,s9,s10);            \
      const float mp = VC(xP, s0,s1,s2_,s3,s4,s5,s6,s7,s8,s9,s10);            \
      SSIMACC                                                                 \
    }                                                                         \
    {                                                                         \
      const float m1 = VC(yA, s0,s1,s2_,s3,s4,s5,s6,s7,s8,s9,s10);            \
      const float m2 = VC(yB, s0,s1,s2_,s3,s4,s5,s6,s7,s8,s9,s10);            \
      const float mq = VC(yQ, s0,s1,s2_,s3,s4,s5,s6,s7,s8,s9,s10);            \
      const float mp = VC(yP, s0,s1,s2_,s3,s4,s5,s6,s7,s8,s9,s10);            \
      SSIMACC                                                                 \
    }                                                                         \
  }

  // Row p of current chunk (input row ib+p): h-conv + (if ready) v-conv.
#define ROWP(p, s0,s1,s2_,s3,s4,s5,s6,s7,s8,s9,s10)                           \
  if (ib + p < NIN) {                                                         \
    HBODY(p)                                                                  \
    if (ib + p >= 2 * PADK) VOUTBODY(s0,s1,s2_,s3,s4,s5,s6,s7,s8,s9,s10)      \
  }

  // Prologue: stage chunk 0 fully.
  LOAD6(0); WRITE6; LOAD5(0); WRITE5;
  __syncthreads();

  // Steady state, 2 barriers/chunk. Next half-chunk global loads issue before
  // the compute phase (latency hides under ~1k VALU); the LDS write lands
  // right after the barrier that retires the old readers (disjoint row sets).
#pragma unroll 1
  for (int o = 0; o < NCHK; ++o) {
    const int ib = 11 * o;
    const int nx = o + 1;
    if (nx < NCHK) LOAD6(nx);
    ROWP(0, 1,2,3,4,5,6,7,8,9,10,0)
    ROWP(1, 2,3,4,5,6,7,8,9,10,0,1)
    ROWP(2, 3,4,5,6,7,8,9,10,0,1,2)
    ROWP(3, 4,5,6,7,8,9,10,0,1,2,3)
    ROWP(4, 5,6,7,8,9,10,0,1,2,3,4)
    ROWP(5, 6,7,8,9,10,0,1,2,3,4,5)
    __syncthreads();
    if (nx < NCHK) { WRITE6 }
    if (nx < NCHK) LOAD5(nx);
    ROWP(6, 7,8,9,10,0,1,2,3,4,5,6)
    ROWP(7, 8,9,10,0,1,2,3,4,5,6,7)
    ROWP(8, 9,10,0,1,2,3,4,5,6,7,8)
    ROWP(9, 10,0,1,2,3,4,5,6,7,8,9)
    ROWP(10, 0,1,2,3,4,5,6,7,8,9,10)
    __syncthreads();
    if (nx < NCHK) { WRITE5 }
  }

  // Block reduction: wave64 shuffle -> LDS -> one double atomic per block.
#pragma unroll
  for (int off = 32; off > 0; off >>= 1) local += __shfl_down(local, off, 64);
  const int wave = t >> 6;
  const int lane = t & 63;
  if (lane == 0) wsum[wave] = local;
  __syncthreads();
  if (t == 0) {
    float s = wsum[0] + wsum[1] + wsum[2] + wsum[3];
    atomicAdd(accum, (double)s);
  }
}

__global__ void ssim_final_kernel(const double* __restrict__ accum,
                                  float* __restrict__ out) {
  out[0] = 1.0f - (float)(accum[0] / NPIX);
}

extern "C" void kernel_launch(void* const* d_in, const int* in_sizes, int n_in,
                              void* d_out, int out_size, void* d_ws, size_t ws_size,
                              hipStream_t stream) {
  const float* img1 = (const float*)d_in[0];
  const float* img2 = (const float*)d_in[1];
  double* accum = (double*)d_ws;
  hipMemsetAsync(accum, 0, sizeof(double), stream);

  dim3 grid(HH / TH, BATCH);
  ssim_main_kernel<<<grid, 256, 0, stream>>>(img1, img2, accum);
  ssim_final_kernel<<<1, 1, 0, stream>>>(accum, (float*)d_out);
}